// Round 1
// baseline (517.217 us; speedup 1.0000x reference)
//
#include <hip/hip_runtime.h>
#include <hip/hip_bf16.h>

// Problem: B=16, S=2048, D=64 attention w/ symmetric pad mask.
// out = [context (B*S*D fp32), attn (B*S*S fp32)] concatenated.
#define NBATCH 16
#define SLEN   2048
#define DIM    64
#define TQ     16      // query rows per block
#define NWAVE  8
#define NTHR   512
#define SROW   2052    // 2048 + 4 pad floats -> row stride 4 banks apart

typedef __attribute__((ext_vector_type(8))) short bf16x8;
typedef __attribute__((ext_vector_type(4))) float f32x4;

__device__ inline short f2bf(float f) {
    union { __hip_bfloat16 h; short s; } u;
    u.h = __float2bfloat16(f);
    return u.s;
}

__device__ inline bf16x8 pack8(float4 a, float4 b) {
    bf16x8 r;
    r[0] = f2bf(a.x); r[1] = f2bf(a.y); r[2] = f2bf(a.z); r[3] = f2bf(a.w);
    r[4] = f2bf(b.x); r[5] = f2bf(b.y); r[6] = f2bf(b.z); r[7] = f2bf(b.w);
    return r;
}

__global__ __launch_bounds__(NTHR, 1) void sdpa_kernel(
    const float* __restrict__ Q, const float* __restrict__ K,
    const float* __restrict__ V, const int* __restrict__ M,
    float* __restrict__ outCtx, float* __restrict__ outAttn)
{
    __shared__ float sS[TQ * SROW];          // unnormalized exp(scores), 128.3 KB
    __shared__ float emult[SLEN];            // 0/1 column mask multiplier, 8 KB
    __shared__ float partial[NWAVE * TQ];    // cross-wave row-sum partials
    __shared__ float scalev[TQ];             // 1/l (0 for masked rows)
    __shared__ float ctxpart[2 * TQ * DIM];  // split-K PV partials, 8 KB

    const int tid = threadIdx.x;
    const int w   = tid >> 6;      // wave id 0..7
    const int l   = tid & 63;      // lane
    const int g   = l >> 4;        // quad group 0..3
    const int c   = l & 15;

    const int b  = blockIdx.x >> 7;      // batch  (S/TQ = 128 tiles/batch)
    const int qt = blockIdx.x & 127;     // query tile
    const int i0 = qt * TQ;

    const float* Qb = Q + ((size_t)b * SLEN + i0) * DIM;
    const float* Kb = K + (size_t)b * SLEN * DIM;
    const float* Vb = V + (size_t)b * SLEN * DIM;
    const int*   Mb = M + b * SLEN;

    // column mask multipliers
    for (int j = tid; j < SLEN; j += NTHR)
        emult[j] = Mb[j] ? 0.0f : 1.0f;

    // Q fragments (A-operand: lane holds Q[i0 + (l&15)][(l>>4)*8 + 0..7], +32)
    bf16x8 qa0, qa1;
    {
        const float* qp = Qb + (size_t)c * DIM + g * 8;
        qa0 = pack8(*(const float4*)(qp),      *(const float4*)(qp + 4));
        qa1 = pack8(*(const float4*)(qp + 32), *(const float4*)(qp + 36));
    }
    __syncthreads();

    // ---- Phase 1: QK^T, exp, stage into LDS, accumulate row sums ----
    float rsum[4] = {0.f, 0.f, 0.f, 0.f};
    const float scl = 0.125f;   // 1/sqrt(64)
    for (int jt = w; jt < SLEN / 16; jt += NWAVE) {
        const int j0 = jt * 16;
        // B-operand: lane holds K[j0 + (l&15)][(l>>4)*8 + 0..7] (contiguous d)
        const float* kp = Kb + (size_t)(j0 + c) * DIM + g * 8;
        bf16x8 kb0 = pack8(*(const float4*)(kp),      *(const float4*)(kp + 4));
        bf16x8 kb1 = pack8(*(const float4*)(kp + 32), *(const float4*)(kp + 36));
        f32x4 acc = {0.f, 0.f, 0.f, 0.f};
        acc = __builtin_amdgcn_mfma_f32_16x16x32_bf16(qa0, kb0, acc, 0, 0, 0);
        acc = __builtin_amdgcn_mfma_f32_16x16x32_bf16(qa1, kb1, acc, 0, 0, 0);
        // C layout: row i = g*4 + r, col j = j0 + c
        const float em = emult[j0 + c];
        #pragma unroll
        for (int r = 0; r < 4; r++) {
            const float e = __expf(acc[r] * scl) * em;
            sS[(g * 4 + r) * SROW + j0 + c] = e;
            rsum[r] += e;
        }
    }
    // reduce across the 16 lanes of each quad group (same 4 rows)
    #pragma unroll
    for (int off = 1; off < 16; off <<= 1) {
        #pragma unroll
        for (int r = 0; r < 4; r++)
            rsum[r] += __shfl_xor(rsum[r], off, 64);
    }
    if (c == 0) {
        #pragma unroll
        for (int r = 0; r < 4; r++)
            partial[w * TQ + g * 4 + r] = rsum[r];
    }
    __syncthreads();
    if (tid < TQ) {
        float lsum = 0.f;
        #pragma unroll
        for (int ww = 0; ww < NWAVE; ww++) lsum += partial[ww * TQ + tid];
        const int rowm = Mb[i0 + tid];
        scalev[tid] = (rowm || lsum <= 0.f) ? 0.f : 1.f / lsum;
    }
    __syncthreads();

    // ---- Phase 3a: write normalized attn (coalesced float4) ----
    {
        const size_t attnBase = ((size_t)b * SLEN + i0) * SLEN;
        const int j = tid * 4;   // NTHR*4 == SLEN: one float4 per thread per row
        for (int i = 0; i < TQ; i++) {
            float4 v = *(const float4*)(sS + i * SROW + j);
            const float sc = scalev[i];
            v.x *= sc; v.y *= sc; v.z *= sc; v.w *= sc;
            *(float4*)(outAttn + attnBase + (size_t)i * SLEN + j) = v;
        }
    }

    // ---- Phase 3b: PV = P(16 x 2048) * V(2048 x 64), split-K over 2 ----
    {
        const int nt = w & 3, kh = w >> 2;
        const int n0 = nt * 16;
        f32x4 acc = {0.f, 0.f, 0.f, 0.f};
        for (int ks = 0; ks < 32; ks++) {
            const int kbase = kh * 1024 + ks * 32;
            // A-operand: P[i = l&15][j = kbase + g*8 + 0..7] from LDS
            const float* pp = sS + c * SROW + kbase + g * 8;
            bf16x8 af = pack8(*(const float4*)(pp), *(const float4*)(pp + 4));
            // B-operand: V[j = kbase + g*8 + jj][d = n0 + c] (strided)
            const float* vp = Vb + (size_t)(kbase + g * 8) * DIM + n0 + c;
            bf16x8 bfr;
            #pragma unroll
            for (int jj = 0; jj < 8; jj++) bfr[jj] = f2bf(vp[(size_t)jj * DIM]);
            acc = __builtin_amdgcn_mfma_f32_16x16x32_bf16(af, bfr, acc, 0, 0, 0);
        }
        // C layout: row i = g*4 + r, col d = n0 + c
        #pragma unroll
        for (int r = 0; r < 4; r++)
            ctxpart[(kh * TQ + g * 4 + r) * DIM + n0 + c] = acc[r];
    }
    __syncthreads();
    // combine split-K halves, normalize, write context
    for (int idx = tid; idx < TQ * DIM; idx += NTHR) {
        const int i = idx >> 6, n = idx & 63;
        const float v = (ctxpart[i * DIM + n] + ctxpart[(TQ + i) * DIM + n]) * scalev[i];
        outCtx[((size_t)b * SLEN + i0 + i) * DIM + n] = v;
    }
}

extern "C" void kernel_launch(void* const* d_in, const int* in_sizes, int n_in,
                              void* d_out, int out_size, void* d_ws, size_t ws_size,
                              hipStream_t stream) {
    const float* Q = (const float*)d_in[0];
    const float* K = (const float*)d_in[1];
    const float* V = (const float*)d_in[2];
    const int*   M = (const int*)d_in[3];   // bool mask -> int32 per harness convention
    float* outCtx  = (float*)d_out;
    float* outAttn = (float*)d_out + (size_t)NBATCH * SLEN * DIM;
    dim3 grid(NBATCH * (SLEN / TQ));   // 2048 blocks
    sdpa_kernel<<<grid, NTHR, 0, stream>>>(Q, K, V, M, outCtx, outAttn);
}